// Round 1
// baseline (202.694 us; speedup 1.0000x reference)
//
#include <hip/hip_runtime.h>

// Trilinear grid_sample (align_corners=False, padding zeros) over a 128^3
// BINARY (0/1 float) grid with 8.4M points.
//
// Strategy: pack each base cell's 8 corner occupancy bits into one byte in a
// 129^3 table (index offset +1 so ix0=-1 boundary needs no special case,
// OOB corners pack to 0 == padding_mode='zeros'). Sampling then needs ONE
// byte gather per point instead of 8 float gathers -> 8x fewer scattered
// addresses, and the 2.05MB table is L2-resident.

constexpr int GS  = 128;          // grid size per dim
constexpr int TD  = GS + 1;       // table dim = 129 (base index in [0,128])
constexpr size_t TBL_SIZE = (size_t)TD * TD * TD;  // ~2.05 MB

// ---------------------------------------------------------------- pack ----
__global__ __launch_bounds__(256)
void pack_kernel(const float* __restrict__ grid, unsigned char* __restrict__ tbl) {
    int i = blockIdx.x * blockDim.x + threadIdx.x;
    if (i >= (int)TBL_SIZE) return;
    int x = i % TD;
    int t = i / TD;
    int y = t % TD;
    int z = t / TD;
    unsigned byte = 0u;
#pragma unroll
    for (int k = 0; k < 8; ++k) {
        int xi = x - 1 + (k & 1);
        int yi = y - 1 + ((k >> 1) & 1);
        int zi = z - 1 + (k >> 2);
        float g = 0.0f;
        if (((unsigned)xi < (unsigned)GS) &
            ((unsigned)yi < (unsigned)GS) &
            ((unsigned)zi < (unsigned)GS))
            g = grid[(zi * GS + yi) * GS + xi];
        byte |= (g != 0.0f ? 1u : 0u) << k;
    }
    tbl[i] = (unsigned char)byte;
}

// -------------------------------------------------------------- sample ----
// 4 points per thread: coords read as 3x float4 (16B/lane), out as float4.
__global__ __launch_bounds__(256)
void sample_packed(const unsigned char* __restrict__ tbl,
                   const float* __restrict__ coords,
                   float* __restrict__ out, int nt) {
    int t = blockIdx.x * blockDim.x + threadIdx.x;
    if (t >= nt) return;
    const float4* c4 = (const float4*)coords;
    float4 a = c4[3 * t + 0];
    float4 b = c4[3 * t + 1];
    float4 c = c4[3 * t + 2];
    float xs[4] = {a.x, a.w, b.z, c.y};
    float ys[4] = {a.y, b.x, b.w, c.z};
    float zs[4] = {a.z, b.y, c.x, c.w};
    float4 res;
    float* r = &res.x;
#pragma unroll
    for (int i = 0; i < 4; ++i) {
        // ix = ((x+1)*128 - 1)*0.5 = x*64 + 63.5
        float ix = fmaf(xs[i], 64.0f, 63.5f);
        float iy = fmaf(ys[i], 64.0f, 63.5f);
        float iz = fmaf(zs[i], 64.0f, 63.5f);
        float fx = floorf(ix), fy = floorf(iy), fz = floorf(iz);
        float wx = ix - fx, wy = iy - fy, wz = iz - fz;
        // base index in table space: floor + 1, in [0,128] for coords in [-1,1]
        int xb = (int)fx + 1, yb = (int)fy + 1, zb = (int)fz + 1;
        // cheap insurance against fp-edge coords (never triggers in-spec):
        xb = min(max(xb, 0), GS); yb = min(max(yb, 0), GS); zb = min(max(zb, 0), GS);
        unsigned byte = (unsigned)tbl[(zb * TD + yb) * TD + xb];
        float v0 = (float)( byte       & 1u);
        float v1 = (float)((byte >> 1) & 1u);
        float v2 = (float)((byte >> 2) & 1u);
        float v3 = (float)((byte >> 3) & 1u);
        float v4 = (float)((byte >> 4) & 1u);
        float v5 = (float)((byte >> 5) & 1u);
        float v6 = (float)((byte >> 6) & 1u);
        float v7 = (float)((byte >> 7) & 1u);
        float c00 = v0 + wx * (v1 - v0);
        float c10 = v2 + wx * (v3 - v2);
        float c01 = v4 + wx * (v5 - v4);
        float c11 = v6 + wx * (v7 - v6);
        float c0  = c00 + wy * (c10 - c00);
        float c1  = c01 + wy * (c11 - c01);
        r[i] = c0 + wz * (c1 - c0);
    }
    ((float4*)out)[t] = res;
}

// ------------------------------------------------- fallback (no ws) ------
__global__ __launch_bounds__(256)
void sample_direct(const float* __restrict__ grid,
                   const float* __restrict__ coords,
                   float* __restrict__ out, int nt) {
    int t = blockIdx.x * blockDim.x + threadIdx.x;
    if (t >= nt) return;
    const float4* c4 = (const float4*)coords;
    float4 a = c4[3 * t + 0];
    float4 b = c4[3 * t + 1];
    float4 c = c4[3 * t + 2];
    float xs[4] = {a.x, a.w, b.z, c.y};
    float ys[4] = {a.y, b.x, b.w, c.z};
    float zs[4] = {a.z, b.y, c.x, c.w};
    float4 res;
    float* r = &res.x;
#pragma unroll
    for (int i = 0; i < 4; ++i) {
        float ix = fmaf(xs[i], 64.0f, 63.5f);
        float iy = fmaf(ys[i], 64.0f, 63.5f);
        float iz = fmaf(zs[i], 64.0f, 63.5f);
        float fx = floorf(ix), fy = floorf(iy), fz = floorf(iz);
        float wx = ix - fx, wy = iy - fy, wz = iz - fz;
        int x0 = (int)fx, y0 = (int)fy, z0 = (int)fz;
        float v[8];
#pragma unroll
        for (int k = 0; k < 8; ++k) {
            int xi = x0 + (k & 1);
            int yi = y0 + ((k >> 1) & 1);
            int zi = z0 + (k >> 2);
            bool ok = ((unsigned)xi < (unsigned)GS) &
                      ((unsigned)yi < (unsigned)GS) &
                      ((unsigned)zi < (unsigned)GS);
            int xc = min(max(xi, 0), GS - 1);
            int yc = min(max(yi, 0), GS - 1);
            int zc = min(max(zi, 0), GS - 1);
            v[k] = grid[(zc * GS + yc) * GS + xc] * (ok ? 1.0f : 0.0f);
        }
        float c00 = v[0] + wx * (v[1] - v[0]);
        float c10 = v[2] + wx * (v[3] - v[2]);
        float c01 = v[4] + wx * (v[5] - v[4]);
        float c11 = v[6] + wx * (v[7] - v[6]);
        float c0  = c00 + wy * (c10 - c00);
        float c1  = c01 + wy * (c11 - c01);
        r[i] = c0 + wz * (c1 - c0);
    }
    ((float4*)out)[t] = res;
}

// -------------------------------------------------------------- launch ----
extern "C" void kernel_launch(void* const* d_in, const int* in_sizes, int n_in,
                              void* d_out, int out_size, void* d_ws, size_t ws_size,
                              hipStream_t stream) {
    const float* grid   = (const float*)d_in[0];
    const float* coords = (const float*)d_in[1];
    float* out = (float*)d_out;
    int npts = in_sizes[1] / 3;
    int nt = npts / 4;  // 8388608/4 = 2097152, divisible by 256

    if (ws_size >= TBL_SIZE) {
        unsigned char* tbl = (unsigned char*)d_ws;
        int pack_blocks = (int)((TBL_SIZE + 255) / 256);
        pack_kernel<<<pack_blocks, 256, 0, stream>>>(grid, tbl);
        sample_packed<<<(nt + 255) / 256, 256, 0, stream>>>(tbl, coords, out, nt);
    } else {
        sample_direct<<<(nt + 255) / 256, 256, 0, stream>>>(grid, coords, out, nt);
    }
}